// Round 2
// baseline (668.414 us; speedup 1.0000x reference)
//
#include <hip/hip_runtime.h>

#define NS 128
#define EPSF 1e-10f
#define FAR_DIST 1e10f

__global__ __launch_bounds__(256) void volrend_kernel(
    const float* __restrict__ rays_d,
    const float* __restrict__ rgb,
    const float* __restrict__ sigma,
    float* __restrict__ rgb_map,
    float* __restrict__ depth_map,
    float* __restrict__ weights,
    float* __restrict__ z_out,
    int N)
{
    const int wave = threadIdx.x >> 6;
    const int lane = threadIdx.x & 63;
    const int ray  = blockIdx.x * 4 + wave;
    if (ray >= N) return;

    // ray direction norm (same address across lanes -> scalar broadcast)
    const float dx = rays_d[ray * 3 + 0];
    const float dy = rays_d[ray * 3 + 1];
    const float dz = rays_d[ray * 3 + 2];
    const float nrm = sqrtf(dx * dx + dy * dy + dz * dz);

    // lane l owns samples 2l and 2l+1
    const int s0 = lane * 2;
    const int s1 = s0 + 1;
    const float z0 = (float)s0 / 127.0f;
    const float z1 = (float)s1 / 127.0f;
    // exact float differences, matching the reference's z[s+1]-z[s]
    const float d0 = ((float)(s0 + 1) / 127.0f - z0) * nrm;
    const float d1 = (s1 == 127 ? FAR_DIST : ((float)(s1 + 1) / 127.0f - z1)) * nrm;

    const size_t base = (size_t)ray * NS;
    const float2 sg = *reinterpret_cast<const float2*>(sigma + base + s0);

    const float a0 = 1.0f - expf(-sg.x * d0);
    const float a1 = 1.0f - expf(-sg.y * d1);

    const float f0 = 1.0f - a0 + EPSF;   // cumprod factor of sample 2l
    const float f1 = 1.0f - a1 + EPSF;   // cumprod factor of sample 2l+1

    // inclusive prefix product of (f0*f1) across lanes (Hillis-Steele, 6 steps)
    float p = f0 * f1;
    #pragma unroll
    for (int off = 1; off < 64; off <<= 1) {
        float t = __shfl_up(p, off);
        if (lane >= off) p *= t;
    }
    const float ex = __shfl_up(p, 1);           // exclusive pair-prefix
    const float trans0 = (lane == 0) ? 1.0f : ex;   // T[2l]   = prod f[0..2l-1]
    const float trans1 = trans0 * f0;               // T[2l+1] = T[2l] * f[2l]

    const float w0 = a0 * trans0;
    const float w1 = a1 * trans1;

    // coalesced vector stores: weights + z_vals
    *reinterpret_cast<float2*>(weights + base + s0) = make_float2(w0, w1);
    *reinterpret_cast<float2*>(z_out   + base + s0) = make_float2(z0, z1);

    // rgb: 6 contiguous floats per lane (24B, 8B-aligned) -> three float2 loads
    const float* rrow = rgb + (size_t)ray * NS * 3 + 6 * lane;
    const float2 v0 = *reinterpret_cast<const float2*>(rrow + 0);
    const float2 v1 = *reinterpret_cast<const float2*>(rrow + 2);
    const float2 v2 = *reinterpret_cast<const float2*>(rrow + 4);
    // sample s0 rgb = (v0.x, v0.y, v1.x); sample s1 rgb = (v1.y, v2.x, v2.y)
    float accr = w0 * v0.x + w1 * v1.y;
    float accg = w0 * v0.y + w1 * v2.x;
    float accb = w0 * v1.x + w1 * v2.y;
    float accd = w0 * z0 + w1 * z1;

    #pragma unroll
    for (int off = 32; off >= 1; off >>= 1) {
        accr += __shfl_down(accr, off);
        accg += __shfl_down(accg, off);
        accb += __shfl_down(accb, off);
        accd += __shfl_down(accd, off);
    }
    if (lane == 0) {
        rgb_map[(size_t)ray * 3 + 0] = accr;
        rgb_map[(size_t)ray * 3 + 1] = accg;
        rgb_map[(size_t)ray * 3 + 2] = accb;
        depth_map[ray] = accd;
    }
}

extern "C" void kernel_launch(void* const* d_in, const int* in_sizes, int n_in,
                              void* d_out, int out_size, void* d_ws, size_t ws_size,
                              hipStream_t stream) {
    // setup_inputs order: rays_o, rays_d, rgb, sigma
    const float* rays_d = (const float*)d_in[1];
    const float* rgb    = (const float*)d_in[2];
    const float* sigma  = (const float*)d_in[3];
    const int N = in_sizes[0] / 3;

    float* out       = (float*)d_out;
    float* rgb_map   = out;                                   // [N,3]
    float* depth_map = out + (size_t)N * 3;                   // [N]
    float* weights   = out + (size_t)N * 4;                   // [N,128]
    float* z_vals    = out + (size_t)N * 4 + (size_t)N * NS;  // [N,128]

    const int blocks = (N + 3) / 4;  // 4 rays (waves) per 256-thread block
    volrend_kernel<<<blocks, 256, 0, stream>>>(
        rays_d, rgb, sigma, rgb_map, depth_map, weights, z_vals, N);
}

// Round 4
// 666.523 us; speedup vs baseline: 1.0028x; 1.0028x over previous
//
#include <hip/hip_runtime.h>

#define NS 128
#define EPSF 1e-10f
#define FAR_DIST 1e10f

__global__ __launch_bounds__(256) void volrend_kernel(
    const float* __restrict__ rays_d,
    const float* __restrict__ rgb,
    const float* __restrict__ sigma,
    float* __restrict__ rgb_map,
    float* __restrict__ depth_map,
    float* __restrict__ weights,
    float* __restrict__ z_out,
    int N)
{
    // 2 rays per wave (32-lane segments), 4 samples per lane
    const int wid  = threadIdx.x >> 6;
    const int lane = threadIdx.x & 63;
    const int half = lane >> 5;        // which ray within the wave
    const int sl   = lane & 31;        // sub-lane within the ray's segment
    const int ray  = (blockIdx.x * 4 + wid) * 2 + half;
    if (ray >= N) return;

    const float dx = rays_d[ray * 3 + 0];
    const float dy = rays_d[ray * 3 + 1];
    const float dz = rays_d[ray * 3 + 2];
    const float nrm = sqrtf(dx * dx + dy * dy + dz * dz);

    // samples s .. s+3
    const int s = sl * 4;
    const float c = 1.0f / 127.0f;     // matches jnp.linspace's i*step
    float z[4], d[4];
    #pragma unroll
    for (int j = 0; j < 4; ++j) {
        z[j] = (float)(s + j) * c;
        const float zn = (float)(s + j + 1) * c;
        d[j] = ((s + j == 127) ? FAR_DIST : (zn - z[j])) * nrm;
    }

    const size_t base = (size_t)ray * NS + s;
    const float4 sg = *reinterpret_cast<const float4*>(sigma + base);

    float a[4], f[4];
    a[0] = 1.0f - __expf(-sg.x * d[0]);
    a[1] = 1.0f - __expf(-sg.y * d[1]);
    a[2] = 1.0f - __expf(-sg.z * d[2]);
    a[3] = 1.0f - __expf(-sg.w * d[3]);
    #pragma unroll
    for (int j = 0; j < 4; ++j) f[j] = 1.0f - a[j] + EPSF;

    // inclusive prefix product of per-lane factor product, width-32 segments
    float p = (f[0] * f[1]) * (f[2] * f[3]);
    #pragma unroll
    for (int off = 1; off < 32; off <<= 1) {
        const float t = __shfl_up(p, off, 32);
        if (sl >= off) p *= t;
    }
    const float ex = __shfl_up(p, 1, 32);
    float t0 = (sl == 0) ? 1.0f : ex;   // T[s]   = prod f[0..s-1]
    const float t1 = t0 * f[0];
    const float t2 = t1 * f[1];
    const float t3 = t2 * f[2];

    const float w0 = a[0] * t0;
    const float w1 = a[1] * t1;
    const float w2 = a[2] * t2;
    const float w3 = a[3] * t3;

    // coalesced 16B stores
    *reinterpret_cast<float4*>(weights + base) = make_float4(w0, w1, w2, w3);
    *reinterpret_cast<float4*>(z_out   + base) = make_float4(z[0], z[1], z[2], z[3]);

    // rgb: 12 contiguous floats per lane (48B, 16B-aligned) as three float4 loads
    const float* rrow = rgb + (size_t)ray * NS * 3 + 12 * sl;
    const float4 u0 = *reinterpret_cast<const float4*>(rrow + 0);
    const float4 u1 = *reinterpret_cast<const float4*>(rrow + 4);
    const float4 u2 = *reinterpret_cast<const float4*>(rrow + 8);
    // element e = 12*sl + k : sample s + k/3, channel k%3
    float accr = w0 * u0.x + w1 * u0.w + w2 * u1.z + w3 * u2.y;
    float accg = w0 * u0.y + w1 * u1.x + w2 * u1.w + w3 * u2.z;
    float accb = w0 * u0.z + w1 * u1.y + w2 * u2.x + w3 * u2.w;
    float accd = w0 * z[0] + w1 * z[1] + w2 * z[2] + w3 * z[3];

    #pragma unroll
    for (int off = 16; off >= 1; off >>= 1) {
        accr += __shfl_down(accr, off, 32);
        accg += __shfl_down(accg, off, 32);
        accb += __shfl_down(accb, off, 32);
        accd += __shfl_down(accd, off, 32);
    }
    if (sl == 0) {
        rgb_map[(size_t)ray * 3 + 0] = accr;
        rgb_map[(size_t)ray * 3 + 1] = accg;
        rgb_map[(size_t)ray * 3 + 2] = accb;
        depth_map[ray] = accd;
    }
}

extern "C" void kernel_launch(void* const* d_in, const int* in_sizes, int n_in,
                              void* d_out, int out_size, void* d_ws, size_t ws_size,
                              hipStream_t stream) {
    // setup_inputs order: rays_o, rays_d, rgb, sigma
    const float* rays_d = (const float*)d_in[1];
    const float* rgb    = (const float*)d_in[2];
    const float* sigma  = (const float*)d_in[3];
    const int N = in_sizes[0] / 3;

    float* out       = (float*)d_out;
    float* rgb_map   = out;                                   // [N,3]
    float* depth_map = out + (size_t)N * 3;                   // [N]
    float* weights   = out + (size_t)N * 4;                   // [N,128]
    float* z_vals    = out + (size_t)N * 4 + (size_t)N * NS;  // [N,128]

    const int blocks = (N + 7) / 8;  // 8 rays per 256-thread block (2 per wave)
    volrend_kernel<<<blocks, 256, 0, stream>>>(
        rays_d, rgb, sigma, rgb_map, depth_map, weights, z_vals, N);
}